// Round 2
// baseline (196.490 us; speedup 1.0000x reference)
//
#include <hip/hip_runtime.h>

// MoE dense: N=16384, D=256, E=8, H=128.
// Plan: bf16 MFMA (fp32 acc) everywhere, biases folded into K-extension,
// expert combine folded into one stacked-K GEMM (K=2048+8 g-columns).
// Workspace layout (needs ~80.5 MB):
//   xb   [16384][288] bf16   @ 0          (col 256 = 1.0 -> bias term, 257.. = 0)
//   w1t  [8][256][288] bf16  @ 9437184    (W1^T per expert, col 256 = b1)
//   wg1t [128][288] bf16     @ 10616832   (Wg1^T, col 256 = bg1)
//   w2t  [256][2080] bf16    @ 10690560   (W2 stacked^T: [d][e*256+h]; cols 2048+e = b2[e][d])
//   g    [16384][8] f32      @ 11755520
//   hw   [16384][2080] bf16  @ 12279808   (cols e*256+h = g*relu(x@W1+b1); 2048+e = g; pad 0)

typedef unsigned short USH;
typedef float f32x4 __attribute__((ext_vector_type(4)));
typedef __bf16 bf16x8 __attribute__((ext_vector_type(8)));

#define AS1 __attribute__((address_space(1)))
#define AS3 __attribute__((address_space(3)))

__device__ __forceinline__ USH f2bf(float f) {
  unsigned int u = __float_as_uint(f);
  u += 0x7fffu + ((u >> 16) & 1u);   // RNE
  return (USH)(u >> 16);
}

__device__ __forceinline__ void gl2lds16(const void* g, void* l) {
  __builtin_amdgcn_global_load_lds((AS1 const void*)g, (AS3 void*)l, 16, 0, 0);
}

// ---------------- prep kernels ----------------

__global__ __launch_bounds__(256) void k_prep_x(const float* __restrict__ x,
                                                USH* __restrict__ xb) {
  int idx = blockIdx.x * 256 + threadIdx.x;       // 16384*36 threads, 8 cols each
  int n = idx / 36, gc = idx % 36;
  int c0 = gc * 8;
  USH v[8];
#pragma unroll
  for (int k = 0; k < 8; ++k) {
    int c = c0 + k;
    float f = (c < 256) ? x[(size_t)n * 256 + c] : (c == 256 ? 1.0f : 0.0f);
    v[k] = f2bf(f);
  }
  *(uint4*)(xb + (size_t)idx * 8) = *(const uint4*)v;
}

__global__ __launch_bounds__(256) void k_prep_w1(const float* __restrict__ W1,
                                                 const float* __restrict__ b1,
                                                 USH* __restrict__ w1t) {
  int idx = blockIdx.x * 256 + threadIdx.x;       // 8*256*288
  int e = idx / 73728;
  int rem = idx % 73728;
  int h = rem / 288, c = rem % 288;
  float v = 0.0f;
  if (c < 256) v = W1[(size_t)e * 65536 + (size_t)c * 256 + h];
  else if (c == 256) v = b1[e * 256 + h];
  w1t[idx] = f2bf(v);
}

__global__ __launch_bounds__(256) void k_prep_wg1(const float* __restrict__ Wg1,
                                                  const float* __restrict__ bg1,
                                                  USH* __restrict__ wg1t) {
  int idx = blockIdx.x * 256 + threadIdx.x;       // 128*288
  int h = idx / 288, c = idx % 288;
  float v = 0.0f;
  if (c < 256) v = Wg1[(size_t)c * 128 + h];
  else if (c == 256) v = bg1[h];
  wg1t[idx] = f2bf(v);
}

__global__ __launch_bounds__(256) void k_prep_w2(const float* __restrict__ W2,
                                                 const float* __restrict__ b2,
                                                 USH* __restrict__ w2t) {
  int idx = blockIdx.x * 256 + threadIdx.x;       // 256*2080
  int d = idx / 2080, kk = idx % 2080;
  float v = 0.0f;
  if (kk < 2048) {
    int e = kk >> 8, h = kk & 255;
    v = W2[(size_t)e * 65536 + (size_t)h * 256 + d];
  } else if (kk < 2056) {
    v = b2[(kk - 2048) * 256 + d];
  }
  w2t[idx] = f2bf(v);
}

// ---------------- gate: g = softmax(relu(x@Wg1+bg1)@Wg2+bg2) ----------------

__global__ __launch_bounds__(256) void k_gate(const USH* __restrict__ xb,
                                              const USH* __restrict__ wg1t,
                                              const float* __restrict__ wg2,
                                              const float* __restrict__ bg2,
                                              float* __restrict__ g,
                                              USH* __restrict__ hw) {
  __shared__ __align__(16) USH As[64 * 32];
  __shared__ __align__(16) USH Bs[128 * 32];
  __shared__ float hg[64 * 129];
  __shared__ float w2s[128 * 8];
  __shared__ float b2s[8];
  __shared__ float lg[64 * 8];

  int tid = threadIdx.x;
  int wave = tid >> 6, lane = tid & 63;
  int quad = lane >> 4, l16 = lane & 15;
  int rowBase = blockIdx.x * 64;

  for (int t = tid; t < 1024; t += 256) w2s[t] = wg2[t];
  if (tid < 8) b2s[tid] = bg2[tid];

  f32x4 acc[8] = {};
  for (int kt = 0; kt < 9; ++kt) {
    int kb = kt * 32;
    {
      int r = tid >> 2, kc = (tid & 3) * 8;
      gl2lds16(xb + (size_t)(rowBase + r) * 288 + kb + kc, As + (size_t)tid * 8);
    }
#pragma unroll
    for (int c = 0; c < 2; ++c) {
      int i = c * 256 + tid;
      int r = i >> 2, kc = (i & 3) * 8;
      gl2lds16(wg1t + (size_t)r * 288 + kb + kc, Bs + (size_t)i * 8);
    }
    __syncthreads();
    bf16x8 av = *(const bf16x8*)(As + (wave * 16 + l16) * 32 + quad * 8);
#pragma unroll
    for (int j = 0; j < 8; ++j) {
      bf16x8 bv = *(const bf16x8*)(Bs + (j * 16 + l16) * 32 + quad * 8);
      acc[j] = __builtin_amdgcn_mfma_f32_16x16x32_bf16(av, bv, acc[j], 0, 0, 0);
    }
    __syncthreads();
  }

#pragma unroll
  for (int j = 0; j < 8; ++j)
#pragma unroll
    for (int r = 0; r < 4; ++r) {
      int row = wave * 16 + quad * 4 + r;
      int col = j * 16 + l16;
      hg[row * 129 + col] = fmaxf(acc[j][r], 0.0f);
    }
  __syncthreads();

  {
    int row = tid >> 2, p = tid & 3;
    float s0 = b2s[p * 2], s1 = b2s[p * 2 + 1];
    for (int k = 0; k < 128; ++k) {
      float h = hg[row * 129 + k];
      s0 += h * w2s[k * 8 + p * 2];
      s1 += h * w2s[k * 8 + p * 2 + 1];
    }
    lg[row * 8 + p * 2] = s0;
    lg[row * 8 + p * 2 + 1] = s1;
  }
  __syncthreads();

  if (tid < 64) {
    float l[8];
    float m = -1e30f;
#pragma unroll
    for (int e = 0; e < 8; ++e) { l[e] = lg[tid * 8 + e]; m = fmaxf(m, l[e]); }
    float s = 0.0f;
#pragma unroll
    for (int e = 0; e < 8; ++e) { l[e] = expf(l[e] - m); s += l[e]; }
    float inv = 1.0f / s;
    size_t grow = rowBase + tid;
#pragma unroll
    for (int e = 0; e < 8; ++e) {
      float ge = l[e] * inv;
      g[grow * 8 + e] = ge;
      hw[grow * 2080 + 2048 + e] = f2bf(ge);
    }
#pragma unroll
    for (int z = 0; z < 24; ++z) hw[grow * 2080 + 2056 + z] = 0;
  }
}

// ---------------- stage 1: hw[:, e*256+h] = g[:,e]*relu(x@W1[e]+b1[e]) ----------------

__global__ __launch_bounds__(256) void k_stage1(const USH* __restrict__ xb,
                                                const USH* __restrict__ w1t,
                                                const float* __restrict__ g,
                                                USH* __restrict__ hw) {
  __shared__ __align__(16) USH As[128 * 32];
  __shared__ __align__(16) USH Bs[128 * 32];
  __shared__ float gs[128];

  int tid = threadIdx.x;
  int wave = tid >> 6, lane = tid & 63;
  int quad = lane >> 4, l16 = lane & 15;
  int wr = wave >> 1, wc = wave & 1;
  int rowBase = blockIdx.x * 128;
  int colBase = blockIdx.y * 128;
  int e = blockIdx.z;

  if (tid < 128) gs[tid] = g[(size_t)(rowBase + tid) * 8 + e];

  const USH* B = w1t + (size_t)e * 256 * 288;

  f32x4 acc[4][4] = {};
  for (int kt = 0; kt < 9; ++kt) {
    int kb = kt * 32;
#pragma unroll
    for (int c = 0; c < 2; ++c) {
      int i = c * 256 + tid;
      int r = i >> 2, kc = (i & 3) * 8;
      gl2lds16(xb + (size_t)(rowBase + r) * 288 + kb + kc, As + (size_t)i * 8);
      gl2lds16(B + (size_t)(colBase + r) * 288 + kb + kc, Bs + (size_t)i * 8);
    }
    __syncthreads();
    bf16x8 av[4], bv[4];
#pragma unroll
    for (int i = 0; i < 4; ++i)
      av[i] = *(const bf16x8*)(As + (wr * 64 + i * 16 + l16) * 32 + quad * 8);
#pragma unroll
    for (int j = 0; j < 4; ++j)
      bv[j] = *(const bf16x8*)(Bs + (wc * 64 + j * 16 + l16) * 32 + quad * 8);
#pragma unroll
    for (int i = 0; i < 4; ++i)
#pragma unroll
      for (int j = 0; j < 4; ++j)
        acc[i][j] = __builtin_amdgcn_mfma_f32_16x16x32_bf16(av[i], bv[j], acc[i][j], 0, 0, 0);
    __syncthreads();
  }

#pragma unroll
  for (int i = 0; i < 4; ++i) {
#pragma unroll
    for (int r = 0; r < 4; ++r) {
      int rl = wr * 64 + i * 16 + quad * 4 + r;
      float gg = gs[rl];
      size_t grow = (size_t)(rowBase + rl);
#pragma unroll
      for (int j = 0; j < 4; ++j) {
        int col = colBase + wc * 64 + j * 16 + l16;
        float v = fmaxf(acc[i][j][r], 0.0f) * gg;
        hw[grow * 2080 + e * 256 + col] = f2bf(v);
      }
    }
  }
}

// ---------------- stage 2: out = hw @ w2t^T  (K=2080 includes g*b2 terms) ----------------

__global__ __launch_bounds__(256) void k_stage2(const USH* __restrict__ hwm,
                                                const USH* __restrict__ w2t,
                                                float* __restrict__ out) {
  __shared__ __align__(16) USH As[128 * 32];
  __shared__ __align__(16) USH Bs[128 * 32];

  int tid = threadIdx.x;
  int wave = tid >> 6, lane = tid & 63;
  int quad = lane >> 4, l16 = lane & 15;
  int wr = wave >> 1, wc = wave & 1;
  int rowBase = blockIdx.x * 128;
  int colBase = blockIdx.y * 128;

  f32x4 acc[4][4] = {};
  for (int kt = 0; kt < 65; ++kt) {
    int kb = kt * 32;
#pragma unroll
    for (int c = 0; c < 2; ++c) {
      int i = c * 256 + tid;
      int r = i >> 2, kc = (i & 3) * 8;
      gl2lds16(hwm + (size_t)(rowBase + r) * 2080 + kb + kc, As + (size_t)i * 8);
      gl2lds16(w2t + (size_t)(colBase + r) * 2080 + kb + kc, Bs + (size_t)i * 8);
    }
    __syncthreads();
    bf16x8 av[4], bv[4];
#pragma unroll
    for (int i = 0; i < 4; ++i)
      av[i] = *(const bf16x8*)(As + (wr * 64 + i * 16 + l16) * 32 + quad * 8);
#pragma unroll
    for (int j = 0; j < 4; ++j)
      bv[j] = *(const bf16x8*)(Bs + (wc * 64 + j * 16 + l16) * 32 + quad * 8);
#pragma unroll
    for (int i = 0; i < 4; ++i)
#pragma unroll
      for (int j = 0; j < 4; ++j)
        acc[i][j] = __builtin_amdgcn_mfma_f32_16x16x32_bf16(av[i], bv[j], acc[i][j], 0, 0, 0);
    __syncthreads();
  }

#pragma unroll
  for (int i = 0; i < 4; ++i) {
#pragma unroll
    for (int r = 0; r < 4; ++r) {
      int rl = wr * 64 + i * 16 + quad * 4 + r;
      size_t grow = (size_t)(rowBase + rl);
#pragma unroll
      for (int j = 0; j < 4; ++j) {
        int col = colBase + wc * 64 + j * 16 + l16;
        out[grow * 256 + col] = acc[i][j][r];
      }
    }
  }
}

// ---------------- launch ----------------

extern "C" void kernel_launch(void* const* d_in, const int* in_sizes, int n_in,
                              void* d_out, int out_size, void* d_ws, size_t ws_size,
                              hipStream_t stream) {
  const float* x   = (const float*)d_in[0];
  const float* Wg1 = (const float*)d_in[1];
  const float* bg1 = (const float*)d_in[2];
  const float* Wg2 = (const float*)d_in[3];
  const float* bg2 = (const float*)d_in[4];
  const float* W1  = (const float*)d_in[5];
  const float* b1  = (const float*)d_in[6];
  const float* W2  = (const float*)d_in[7];
  const float* b2  = (const float*)d_in[8];
  float* out = (float*)d_out;

  char* ws = (char*)d_ws;
  USH*   xb   = (USH*)(ws);
  USH*   w1t  = (USH*)(ws + 9437184);
  USH*   wg1t = (USH*)(ws + 10616832);
  USH*   w2t  = (USH*)(ws + 10690560);
  float* g    = (float*)(ws + 11755520);
  USH*   hw   = (USH*)(ws + 12279808);   // needs total 80,437,248 B of ws

  hipLaunchKernelGGL(k_prep_x,   dim3(2304), dim3(256), 0, stream, x, xb);
  hipLaunchKernelGGL(k_prep_w1,  dim3(2304), dim3(256), 0, stream, W1, b1, w1t);
  hipLaunchKernelGGL(k_prep_wg1, dim3(144),  dim3(256), 0, stream, Wg1, bg1, wg1t);
  hipLaunchKernelGGL(k_prep_w2,  dim3(2080), dim3(256), 0, stream, W2, b2, w2t);
  hipLaunchKernelGGL(k_gate,     dim3(256),  dim3(256), 0, stream, xb, wg1t, Wg2, bg2, g, hw);
  hipLaunchKernelGGL(k_stage1,   dim3(128, 2, 8), dim3(256), 0, stream, xb, w1t, g, hw);
  hipLaunchKernelGGL(k_stage2,   dim3(128, 2),    dim3(256), 0, stream, hw, w2t, out);
}

// Round 3
// 181.128 us; speedup vs baseline: 1.0848x; 1.0848x over previous
//
#include <hip/hip_runtime.h>

// MoE dense: N=16384, D=256, E=8, H=128.
// bf16 MFMA (fp32 acc), biases folded into K-extension, expert combine folded
// into one stacked-K GEMM (K=2048+8 g-columns).
// R3: stage2 tile 128x128->64x128 (grid 256 -> 512 blocks = 2 blocks/CU; was
//     occupancy-starved at 10.7%); 4 prep kernels fused into 1.
// Workspace layout (~80.5 MB):
//   xb   [16384][288] bf16   @ 0          (col 256 = 1.0 -> bias, 257.. = 0)
//   w1t  [8][256][288] bf16  @ 9437184    (W1^T per expert, col 256 = b1)
//   wg1t [128][288] bf16     @ 10616832   (Wg1^T, col 256 = bg1)
//   w2t  [256][2080] bf16    @ 10690560   (cols 2048+e = b2[e][d])
//   g    [16384][8] f32      @ 11755520
//   hw   [16384][2080] bf16  @ 12279808   (e*256+h = g*relu(.); 2048+e = g)

typedef unsigned short USH;
typedef float f32x4 __attribute__((ext_vector_type(4)));
typedef __bf16 bf16x8 __attribute__((ext_vector_type(8)));

#define AS1 __attribute__((address_space(1)))
#define AS3 __attribute__((address_space(3)))

__device__ __forceinline__ USH f2bf(float f) {
  unsigned int u = __float_as_uint(f);
  u += 0x7fffu + ((u >> 16) & 1u);   // RNE
  return (USH)(u >> 16);
}

__device__ __forceinline__ void gl2lds16(const void* g, void* l) {
  __builtin_amdgcn_global_load_lds((AS1 const void*)g, (AS3 void*)l, 16, 0, 0);
}

// ---------------- fused prep kernel ----------------
// blocks [0,2304): xb; [2304,4608): w1t; [4608,4752): wg1t; [4752,6832): w2t

__global__ __launch_bounds__(256) void k_prep_all(
    const float* __restrict__ x,
    const float* __restrict__ Wg1, const float* __restrict__ bg1,
    const float* __restrict__ W1,  const float* __restrict__ b1,
    const float* __restrict__ W2,  const float* __restrict__ b2,
    USH* __restrict__ xb, USH* __restrict__ wg1t,
    USH* __restrict__ w1t, USH* __restrict__ w2t) {
  int b = blockIdx.x;
  if (b < 2304) {
    int idx = b * 256 + threadIdx.x;            // 16384*36 threads, 8 cols each
    int n = idx / 36, gc = idx % 36;
    int c0 = gc * 8;
    USH v[8];
#pragma unroll
    for (int k = 0; k < 8; ++k) {
      int c = c0 + k;
      float f = (c < 256) ? x[(size_t)n * 256 + c] : (c == 256 ? 1.0f : 0.0f);
      v[k] = f2bf(f);
    }
    *(uint4*)(xb + (size_t)idx * 8) = *(const uint4*)v;
  } else if (b < 4608) {
    int idx = (b - 2304) * 256 + threadIdx.x;   // 8*256*288
    int e = idx / 73728;
    int rem = idx % 73728;
    int h = rem / 288, c = rem % 288;
    float v = 0.0f;
    if (c < 256) v = W1[(size_t)e * 65536 + (size_t)c * 256 + h];
    else if (c == 256) v = b1[e * 256 + h];
    w1t[idx] = f2bf(v);
  } else if (b < 4752) {
    int idx = (b - 4608) * 256 + threadIdx.x;   // 128*288
    int h = idx / 288, c = idx % 288;
    float v = 0.0f;
    if (c < 256) v = Wg1[(size_t)c * 128 + h];
    else if (c == 256) v = bg1[h];
    wg1t[idx] = f2bf(v);
  } else {
    int idx = (b - 4752) * 256 + threadIdx.x;   // 256*2080
    int d = idx / 2080, kk = idx % 2080;
    float v = 0.0f;
    if (kk < 2048) {
      int e = kk >> 8, h = kk & 255;
      v = W2[(size_t)e * 65536 + (size_t)h * 256 + d];
    } else if (kk < 2056) {
      v = b2[(kk - 2048) * 256 + d];
    }
    w2t[idx] = f2bf(v);
  }
}

// ---------------- gate: g = softmax(relu(x@Wg1+bg1)@Wg2+bg2) ----------------

__global__ __launch_bounds__(256) void k_gate(const USH* __restrict__ xb,
                                              const USH* __restrict__ wg1t,
                                              const float* __restrict__ wg2,
                                              const float* __restrict__ bg2,
                                              float* __restrict__ g,
                                              USH* __restrict__ hw) {
  __shared__ __align__(16) USH As[64 * 32];
  __shared__ __align__(16) USH Bs[128 * 32];
  __shared__ float hg[64 * 129];
  __shared__ float w2s[128 * 8];
  __shared__ float b2s[8];
  __shared__ float lg[64 * 8];

  int tid = threadIdx.x;
  int wave = tid >> 6, lane = tid & 63;
  int quad = lane >> 4, l16 = lane & 15;
  int rowBase = blockIdx.x * 64;

  for (int t = tid; t < 1024; t += 256) w2s[t] = wg2[t];
  if (tid < 8) b2s[tid] = bg2[tid];

  f32x4 acc[8] = {};
  for (int kt = 0; kt < 9; ++kt) {
    int kb = kt * 32;
    {
      int r = tid >> 2, kc = (tid & 3) * 8;
      gl2lds16(xb + (size_t)(rowBase + r) * 288 + kb + kc, As + (size_t)tid * 8);
    }
#pragma unroll
    for (int c = 0; c < 2; ++c) {
      int i = c * 256 + tid;
      int r = i >> 2, kc = (i & 3) * 8;
      gl2lds16(wg1t + (size_t)r * 288 + kb + kc, Bs + (size_t)i * 8);
    }
    __syncthreads();
    bf16x8 av = *(const bf16x8*)(As + (wave * 16 + l16) * 32 + quad * 8);
#pragma unroll
    for (int j = 0; j < 8; ++j) {
      bf16x8 bv = *(const bf16x8*)(Bs + (j * 16 + l16) * 32 + quad * 8);
      acc[j] = __builtin_amdgcn_mfma_f32_16x16x32_bf16(av, bv, acc[j], 0, 0, 0);
    }
    __syncthreads();
  }

#pragma unroll
  for (int j = 0; j < 8; ++j)
#pragma unroll
    for (int r = 0; r < 4; ++r) {
      int row = wave * 16 + quad * 4 + r;
      int col = j * 16 + l16;
      hg[row * 129 + col] = fmaxf(acc[j][r], 0.0f);
    }
  __syncthreads();

  {
    int row = tid >> 2, p = tid & 3;
    float s0 = b2s[p * 2], s1 = b2s[p * 2 + 1];
    for (int k = 0; k < 128; ++k) {
      float h = hg[row * 129 + k];
      s0 += h * w2s[k * 8 + p * 2];
      s1 += h * w2s[k * 8 + p * 2 + 1];
    }
    lg[row * 8 + p * 2] = s0;
    lg[row * 8 + p * 2 + 1] = s1;
  }
  __syncthreads();

  if (tid < 64) {
    float l[8];
    float m = -1e30f;
#pragma unroll
    for (int e = 0; e < 8; ++e) { l[e] = lg[tid * 8 + e]; m = fmaxf(m, l[e]); }
    float s = 0.0f;
#pragma unroll
    for (int e = 0; e < 8; ++e) { l[e] = expf(l[e] - m); s += l[e]; }
    float inv = 1.0f / s;
    size_t grow = rowBase + tid;
#pragma unroll
    for (int e = 0; e < 8; ++e) {
      float ge = l[e] * inv;
      g[grow * 8 + e] = ge;
      hw[grow * 2080 + 2048 + e] = f2bf(ge);
    }
#pragma unroll
    for (int z = 0; z < 24; ++z) hw[grow * 2080 + 2056 + z] = 0;
  }
}

// ---------------- stage 1: hw[:, e*256+h] = g[:,e]*relu(x@W1[e]+b1[e]) ----------------

__global__ __launch_bounds__(256) void k_stage1(const USH* __restrict__ xb,
                                                const USH* __restrict__ w1t,
                                                const float* __restrict__ g,
                                                USH* __restrict__ hw) {
  __shared__ __align__(16) USH As[128 * 32];
  __shared__ __align__(16) USH Bs[128 * 32];
  __shared__ float gs[128];

  int tid = threadIdx.x;
  int wave = tid >> 6, lane = tid & 63;
  int quad = lane >> 4, l16 = lane & 15;
  int wr = wave >> 1, wc = wave & 1;
  int rowBase = blockIdx.x * 128;
  int colBase = blockIdx.y * 128;
  int e = blockIdx.z;

  if (tid < 128) gs[tid] = g[(size_t)(rowBase + tid) * 8 + e];

  const USH* B = w1t + (size_t)e * 256 * 288;

  f32x4 acc[4][4] = {};
  for (int kt = 0; kt < 9; ++kt) {
    int kb = kt * 32;
#pragma unroll
    for (int c = 0; c < 2; ++c) {
      int i = c * 256 + tid;
      int r = i >> 2, kc = (i & 3) * 8;
      gl2lds16(xb + (size_t)(rowBase + r) * 288 + kb + kc, As + (size_t)i * 8);
      gl2lds16(B + (size_t)(colBase + r) * 288 + kb + kc, Bs + (size_t)i * 8);
    }
    __syncthreads();
    bf16x8 av[4], bv[4];
#pragma unroll
    for (int i = 0; i < 4; ++i)
      av[i] = *(const bf16x8*)(As + (wr * 64 + i * 16 + l16) * 32 + quad * 8);
#pragma unroll
    for (int j = 0; j < 4; ++j)
      bv[j] = *(const bf16x8*)(Bs + (wc * 64 + j * 16 + l16) * 32 + quad * 8);
#pragma unroll
    for (int i = 0; i < 4; ++i)
#pragma unroll
      for (int j = 0; j < 4; ++j)
        acc[i][j] = __builtin_amdgcn_mfma_f32_16x16x32_bf16(av[i], bv[j], acc[i][j], 0, 0, 0);
    __syncthreads();
  }

#pragma unroll
  for (int i = 0; i < 4; ++i) {
#pragma unroll
    for (int r = 0; r < 4; ++r) {
      int rl = wr * 64 + i * 16 + quad * 4 + r;
      float gg = gs[rl];
      size_t grow = (size_t)(rowBase + rl);
#pragma unroll
      for (int j = 0; j < 4; ++j) {
        int col = colBase + wc * 64 + j * 16 + l16;
        float v = fmaxf(acc[i][j][r], 0.0f) * gg;
        hw[grow * 2080 + e * 256 + col] = f2bf(v);
      }
    }
  }
}

// ---------------- stage 2: out = hw @ w2t^T  (K=2080 includes g*b2 terms) ----
// R3: 64x128 tile, grid (256,2) = 512 blocks = 2 blocks/CU (was 1 -> 10.7% occ).

__global__ __launch_bounds__(256) void k_stage2(const USH* __restrict__ hwm,
                                                const USH* __restrict__ w2t,
                                                float* __restrict__ out) {
  __shared__ __align__(16) USH As[64 * 32];
  __shared__ __align__(16) USH Bs[128 * 32];

  int tid = threadIdx.x;
  int wave = tid >> 6, lane = tid & 63;
  int quad = lane >> 4, l16 = lane & 15;
  int wr = wave >> 1, wc = wave & 1;       // row half (32), col half (64)
  int rowBase = blockIdx.x * 64;
  int colBase = blockIdx.y * 128;

  f32x4 acc[2][4] = {};
  for (int kt = 0; kt < 65; ++kt) {
    int kb = kt * 32;
    {
      int r = tid >> 2, kc = (tid & 3) * 8;  // As: 64 rows, 1 chunk/thread
      gl2lds16(hwm + (size_t)(rowBase + r) * 2080 + kb + kc, As + (size_t)tid * 8);
    }
#pragma unroll
    for (int c = 0; c < 2; ++c) {            // Bs: 128 rows, 2 chunks/thread
      int i = c * 256 + tid;
      int r = i >> 2, kc = (i & 3) * 8;
      gl2lds16(w2t + (size_t)(colBase + r) * 2080 + kb + kc, Bs + (size_t)i * 8);
    }
    __syncthreads();
    bf16x8 av[2], bv[4];
#pragma unroll
    for (int i = 0; i < 2; ++i)
      av[i] = *(const bf16x8*)(As + (wr * 32 + i * 16 + l16) * 32 + quad * 8);
#pragma unroll
    for (int j = 0; j < 4; ++j)
      bv[j] = *(const bf16x8*)(Bs + (wc * 64 + j * 16 + l16) * 32 + quad * 8);
#pragma unroll
    for (int i = 0; i < 2; ++i)
#pragma unroll
      for (int j = 0; j < 4; ++j)
        acc[i][j] = __builtin_amdgcn_mfma_f32_16x16x32_bf16(av[i], bv[j], acc[i][j], 0, 0, 0);
    __syncthreads();
  }

#pragma unroll
  for (int i = 0; i < 2; ++i) {
#pragma unroll
    for (int r = 0; r < 4; ++r) {
      int rl = wr * 32 + i * 16 + quad * 4 + r;
      size_t grow = (size_t)(rowBase + rl);
#pragma unroll
      for (int j = 0; j < 4; ++j) {
        int col = colBase + wc * 64 + j * 16 + l16;
        out[grow * 256 + col] = acc[i][j][r];
      }
    }
  }
}

// ---------------- launch ----------------

extern "C" void kernel_launch(void* const* d_in, const int* in_sizes, int n_in,
                              void* d_out, int out_size, void* d_ws, size_t ws_size,
                              hipStream_t stream) {
  const float* x   = (const float*)d_in[0];
  const float* Wg1 = (const float*)d_in[1];
  const float* bg1 = (const float*)d_in[2];
  const float* Wg2 = (const float*)d_in[3];
  const float* bg2 = (const float*)d_in[4];
  const float* W1  = (const float*)d_in[5];
  const float* b1  = (const float*)d_in[6];
  const float* W2  = (const float*)d_in[7];
  const float* b2  = (const float*)d_in[8];
  float* out = (float*)d_out;

  char* ws = (char*)d_ws;
  USH*   xb   = (USH*)(ws);
  USH*   w1t  = (USH*)(ws + 9437184);
  USH*   wg1t = (USH*)(ws + 10616832);
  USH*   w2t  = (USH*)(ws + 10690560);
  float* g    = (float*)(ws + 11755520);
  USH*   hw   = (USH*)(ws + 12279808);   // needs total 80,437,248 B of ws

  hipLaunchKernelGGL(k_prep_all, dim3(6832), dim3(256), 0, stream,
                     x, Wg1, bg1, W1, b1, W2, b2, xb, wg1t, w1t, w2t);
  hipLaunchKernelGGL(k_gate,   dim3(256),       dim3(256), 0, stream, xb, wg1t, Wg2, bg2, g, hw);
  hipLaunchKernelGGL(k_stage1, dim3(128, 2, 8), dim3(256), 0, stream, xb, w1t, g, hw);
  hipLaunchKernelGGL(k_stage2, dim3(256, 2),    dim3(256), 0, stream, hw, w2t, out);
}